// Round 1
// baseline (217.711 us; speedup 1.0000x reference)
//
#include <hip/hip_runtime.h>

#define NROWS 8192
#define DIM 128

typedef _Float16 f16x8 __attribute__((ext_vector_type(8)));
typedef float f32x16 __attribute__((ext_vector_type(16)));

// ---------------------------------------------------------------------------
// Kernel 1: per-row L2 normalize of z1/z2 (fp32, matching reference), emit
//   - zh  : normalized z1 cast to fp16 (row-major N x 128)
//   - sq  : ||n1_i||^2 in fp32 (reference computes sq from normalized z1)
//   - sums[0] += s_pos_i  (double atomic)
// One wave (64 threads) per row; each lane owns elements d and d+64.
// ---------------------------------------------------------------------------
__global__ void fmicl_normalize(const float* __restrict__ z1,
                                const float* __restrict__ z2,
                                float* __restrict__ sq,
                                _Float16* __restrict__ zh,
                                double* __restrict__ sums) {
  const int row = blockIdx.x;
  const int lane = threadIdx.x;  // 0..63
  const float* r1 = z1 + (size_t)row * DIM;
  const float* r2 = z2 + (size_t)row * DIM;
  float a0 = r1[lane], a1 = r1[lane + 64];
  float b0 = r2[lane], b1 = r2[lane + 64];
  float s1 = a0 * a0 + a1 * a1;
  float s2 = b0 * b0 + b1 * b1;
#pragma unroll
  for (int off = 32; off; off >>= 1) {
    s1 += __shfl_xor(s1, off);
    s2 += __shfl_xor(s2, off);
  }
  const float inv1 = 1.0f / fmaxf(sqrtf(s1), 1e-12f);
  const float inv2 = 1.0f / fmaxf(sqrtf(s2), 1e-12f);
  const float n1a = a0 * inv1, n1b = a1 * inv1;
  const float n2a = b0 * inv2, n2b = b1 * inv2;
  float sqp = n1a * n1a + n1b * n1b;
  const float da = n1a - n2a, db = n1b - n2b;
  float dp = da * da + db * db;
#pragma unroll
  for (int off = 32; off; off >>= 1) {
    sqp += __shfl_xor(sqp, off);
    dp += __shfl_xor(dp, off);
  }
  zh[(size_t)row * DIM + lane] = (_Float16)n1a;
  zh[(size_t)row * DIM + lane + 64] = (_Float16)n1b;
  if (lane == 0) {
    sq[row] = sqp;
    // s_pos = log(exp(-d_pos/2) + EPS) + 1
    const float spos = logf(expf(-0.5f * dp) + 1e-8f) + 1.0f;
    atomicAdd(&sums[0], (double)spos);
  }
}

// ---------------------------------------------------------------------------
// Kernel 2: fused Gram tile + exp epilogue + reduction.
// Block = 256 threads (4 waves, 2x2), tile 128x128, K = 128 (full D, staged
// once). Wave computes 64x64 = 2x2 tiles of v_mfma_f32_32x32x16_f16.
// LDS: two 128x128 f16 panels (exactly 64 KiB), 16B-granule XOR swizzle
// (gran ^= row&7) to avoid the 32-way bank conflict of stride-256B rows.
// Symmetry: only ct >= rt blocks do work; off-diagonal tiles weighted x2.
// ---------------------------------------------------------------------------
__global__ __launch_bounds__(256, 2) void fmicl_pairwise(
    const _Float16* __restrict__ zh,
    const float* __restrict__ sq,
    double* __restrict__ sums) {
  const int rt = blockIdx.y;
  const int ct = blockIdx.x;
  if (ct < rt) return;  // uniform per block: whole block exits

  __shared__ _Float16 As[128 * 128];
  __shared__ _Float16 Bs[128 * 128];

  const int tid = threadIdx.x;
  const int lane = tid & 63;
  const int wid = tid >> 6;
  const int i0 = rt << 7;
  const int j0 = ct << 7;

  // ---- stage both panels (reg-staged so we can swizzle the LDS address) ----
  const uint4* __restrict__ gA = (const uint4*)(zh + (size_t)i0 * DIM);
  const uint4* __restrict__ gB = (const uint4*)(zh + (size_t)j0 * DIM);
  uint4* sA = (uint4*)As;
  uint4* sB = (uint4*)Bs;
#pragma unroll
  for (int it = 0; it < 8; ++it) {
    const int g = tid + it * 256;   // granule id: 128 rows x 16 granules(16B)
    const int r = g >> 4;
    const int c = g & 15;
    const uint4 va = gA[g];
    const uint4 vb = gB[g];
    const int cs = c ^ (r & 7);     // XOR swizzle within the row
    sA[r * 16 + cs] = va;
    sB[r * 16 + cs] = vb;
  }
  __syncthreads();

  const int l31 = lane & 31;
  const int lhi = lane >> 5;
  const int wm = (wid >> 1) * 64;   // wave sub-tile origin inside 128x128
  const int wn = (wid & 1) * 64;

  f32x16 acc[2][2] = {};
#pragma unroll
  for (int ks = 0; ks < 8; ++ks) {
    f16x8 af[2], bf[2];
#pragma unroll
    for (int mi = 0; mi < 2; ++mi) {
      const int ra = wm + mi * 32 + l31;
      const uint4 va = sA[ra * 16 + ((ks * 2 + lhi) ^ (ra & 7))];
      af[mi] = __builtin_bit_cast(f16x8, va);
      const int rb = wn + mi * 32 + l31;
      const uint4 vb = sB[rb * 16 + ((ks * 2 + lhi) ^ (rb & 7))];
      bf[mi] = __builtin_bit_cast(f16x8, vb);
    }
#pragma unroll
    for (int mi = 0; mi < 2; ++mi)
#pragma unroll
      for (int ni = 0; ni < 2; ++ni)
        acc[mi][ni] = __builtin_amdgcn_mfma_f32_32x32x16_f16(
            af[mi], bf[ni], acc[mi][ni], 0, 0, 0);
  }

  // ---- epilogue: d2 = sq_i + sq_j - 2*dot; g = exp(-d2/2); mask diagonal ----
  // Verified C/D layout (32x32): col = lane&31, row = (reg&3)+8*(reg>>2)+4*(lane>>5)
  float gsum = 0.0f;
#pragma unroll
  for (int mi = 0; mi < 2; ++mi) {
    float4 sqi_q[4];
#pragma unroll
    for (int q = 0; q < 4; ++q)
      sqi_q[q] = *(const float4*)&sq[i0 + wm + mi * 32 + 4 * lhi + 8 * q];
#pragma unroll
    for (int ni = 0; ni < 2; ++ni) {
      const int n = wn + ni * 32 + l31;
      const float sj = sq[j0 + n];
#pragma unroll
      for (int r = 0; r < 16; ++r) {
        const int mloc = (r & 3) + 4 * lhi + 8 * (r >> 2);
        const float si = ((const float*)&sqi_q[r >> 2])[r & 3];
        const float dot = acc[mi][ni][r];
        const float d2 = fmaxf(si + sj - 2.0f * dot, 0.0f);
        const float gg = __expf(-0.5f * d2);
        const int gi = i0 + wm + mi * 32 + mloc;
        const int gj = j0 + n;
        gsum += (gi != gj) ? gg : 0.0f;
      }
    }
  }
#pragma unroll
  for (int off = 32; off; off >>= 1) gsum += __shfl_xor(gsum, off);
  if (lane == 0) {
    const double w = (rt == ct) ? 1.0 : 2.0;  // off-diagonal tiles mirrored
    atomicAdd(&sums[1], w * (double)gsum);
  }
}

// ---------------------------------------------------------------------------
// Kernel 3: assemble scalar loss.
// star_neg = g + EPS exactly, so star_mean = neg_sum/(N(N-1)) + EPS.
// ---------------------------------------------------------------------------
__global__ void fmicl_finalize(const double* __restrict__ sums,
                               float* __restrict__ out) {
  const double pos_mean = sums[0] / (double)NROWS;
  const double star_mean =
      sums[1] / ((double)NROWS * (double)(NROWS - 1)) + 1e-8;
  out[0] = (float)(-pos_mean + 1.5 * star_mean);
}

extern "C" void kernel_launch(void* const* d_in, const int* in_sizes, int n_in,
                              void* d_out, int out_size, void* d_ws,
                              size_t ws_size, hipStream_t stream) {
  const float* z1 = (const float*)d_in[0];
  const float* z2 = (const float*)d_in[1];
  float* out = (float*)d_out;
  char* ws = (char*)d_ws;

  // ws layout: [0..15] two double accumulators (pos, neg); pad to 64;
  // [64 ..) sq (8192 f32 = 32 KiB); then zh (8192*128 f16 = 2 MiB, 16B aligned)
  double* sums = (double*)ws;
  float* sq = (float*)(ws + 64);
  _Float16* zh = (_Float16*)(ws + 64 + sizeof(float) * NROWS);

  hipMemsetAsync(ws, 0, 64, stream);  // zero the accumulators (capture-safe)
  fmicl_normalize<<<NROWS, 64, 0, stream>>>(z1, z2, sq, zh, sums);
  dim3 grid(NROWS / 128, NROWS / 128);
  fmicl_pairwise<<<grid, 256, 0, stream>>>(zh, sq, sums);
  fmicl_finalize<<<1, 1, 0, stream>>>(sums, out);
}

// Round 2
// 41.662 us; speedup vs baseline: 5.2256x; 5.2256x over previous
//
#include <hip/hip_runtime.h>

#define NROWS 8192
#define DIM 128
#define NT 128          // 8192 / 64 tiles per side
#define NPAIRBLK (NT * NT)   // 16384 pairwise blocks (half early-exit)
#define NNORMBLK 2048        // normalize blocks (4 rows each)
#define NREDA 96             // stage-1 reduce blocks

typedef _Float16 f16x8 __attribute__((ext_vector_type(8)));
typedef float f32x16 __attribute__((ext_vector_type(16)));

// ---------------------------------------------------------------------------
// Kernel 1: per-row L2 normalize (fp32, as reference). 256 threads = 4 waves,
// one wave per row. Emits zh (f16 normalized z1), sq (fp32 row norms of n1),
// spos[row] (positive-term per-row scalar). No atomics.
// ---------------------------------------------------------------------------
__global__ void fmicl_normalize(const float* __restrict__ z1,
                                const float* __restrict__ z2,
                                float* __restrict__ sq,
                                _Float16* __restrict__ zh,
                                float* __restrict__ spos) {
  const int row = blockIdx.x * 4 + (threadIdx.x >> 6);
  const int lane = threadIdx.x & 63;
  const float* r1 = z1 + (size_t)row * DIM;
  const float* r2 = z2 + (size_t)row * DIM;
  float a0 = r1[lane], a1 = r1[lane + 64];
  float b0 = r2[lane], b1 = r2[lane + 64];
  float s1 = a0 * a0 + a1 * a1;
  float s2 = b0 * b0 + b1 * b1;
#pragma unroll
  for (int off = 32; off; off >>= 1) {
    s1 += __shfl_xor(s1, off);
    s2 += __shfl_xor(s2, off);
  }
  const float inv1 = 1.0f / fmaxf(sqrtf(s1), 1e-12f);
  const float inv2 = 1.0f / fmaxf(sqrtf(s2), 1e-12f);
  const float n1a = a0 * inv1, n1b = a1 * inv1;
  const float n2a = b0 * inv2, n2b = b1 * inv2;
  float sqp = n1a * n1a + n1b * n1b;
  const float da = n1a - n2a, db = n1b - n2b;
  float dp = da * da + db * db;
#pragma unroll
  for (int off = 32; off; off >>= 1) {
    sqp += __shfl_xor(sqp, off);
    dp += __shfl_xor(dp, off);
  }
  zh[(size_t)row * DIM + lane] = (_Float16)n1a;
  zh[(size_t)row * DIM + lane + 64] = (_Float16)n1b;
  if (lane == 0) {
    sq[row] = sqp;
    spos[row] = logf(expf(-0.5f * dp) + 1e-8f) + 1.0f;  // f'(g_pos)
  }
}

// ---------------------------------------------------------------------------
// Kernel 2: fused Gram 64x64 tile + exp epilogue. 256 threads = 4 waves, each
// wave one 32x32 MFMA chain (8 x v_mfma_f32_32x32x16_f16 over K=128).
// LDS 32 KiB (two 64x128 f16 panels) -> 4 blocks/CU. XOR swizzle ^(r&15):
// 2-way read aliasing (free). Symmetry: ct>=rt only, off-diag weighted x2.
// Per-block partial written to pairP[bid]; early-exit blocks write 0 so the
// workspace never needs re-zeroing between graph replays.
// ---------------------------------------------------------------------------
__global__ __launch_bounds__(256, 4) void fmicl_pairwise(
    const _Float16* __restrict__ zh,
    const float* __restrict__ sq,
    float* __restrict__ pairP) {
  const int rt = blockIdx.y;
  const int ct = blockIdx.x;
  const int bid = rt * NT + ct;
  const int tid = threadIdx.x;
  if (ct < rt) {            // uniform per block
    if (tid == 0) pairP[bid] = 0.0f;
    return;
  }

  __shared__ _Float16 As[64 * DIM];
  __shared__ _Float16 Bs[64 * DIM];
  __shared__ float wsum[4];

  const int lane = tid & 63;
  const int wid = tid >> 6;
  const int i0 = rt << 6;
  const int j0 = ct << 6;

  // ---- stage both panels (coalesced; reg-staged so LDS addr is swizzled) ----
  const uint4* __restrict__ gA = (const uint4*)(zh + (size_t)i0 * DIM);
  const uint4* __restrict__ gB = (const uint4*)(zh + (size_t)j0 * DIM);
  uint4* sA = (uint4*)As;
  uint4* sB = (uint4*)Bs;
#pragma unroll
  for (int it = 0; it < 4; ++it) {
    const int g = tid + it * 256;   // 64 rows x 16 granules (16B)
    const int r = g >> 4;
    const int c = g & 15;
    const uint4 va = gA[g];
    const uint4 vb = gB[g];
    const int cs = c ^ (r & 15);
    sA[r * 16 + cs] = va;
    sB[r * 16 + cs] = vb;
  }
  __syncthreads();

  const int l31 = lane & 31;
  const int lhi = lane >> 5;
  const int wm = (wid >> 1) * 32;   // wave sub-tile origin inside 64x64
  const int wn = (wid & 1) * 32;

  const int ra = wm + l31;
  const int rb = wn + l31;
  f32x16 acc = {};
#pragma unroll
  for (int ks = 0; ks < 8; ++ks) {
    const uint4 va = sA[ra * 16 + ((ks * 2 + lhi) ^ (ra & 15))];
    const uint4 vb = sB[rb * 16 + ((ks * 2 + lhi) ^ (rb & 15))];
    acc = __builtin_amdgcn_mfma_f32_32x32x16_f16(
        __builtin_bit_cast(f16x8, va), __builtin_bit_cast(f16x8, vb), acc,
        0, 0, 0);
  }

  // ---- epilogue: d2 = sq_i + sq_j - 2*dot; g = exp(-d2/2); mask diagonal ----
  // C/D layout (32x32): col = lane&31, row = (reg&3)+8*(reg>>2)+4*(lane>>5)
  float4 sqi_q[4];
#pragma unroll
  for (int q = 0; q < 4; ++q)
    sqi_q[q] = *(const float4*)&sq[i0 + wm + 4 * lhi + 8 * q];
  const int gj = j0 + wn + l31;
  const float sj = sq[gj];
  float gsum = 0.0f;
#pragma unroll
  for (int r = 0; r < 16; ++r) {
    const int mloc = (r & 3) + 4 * lhi + 8 * (r >> 2);
    const float si = ((const float*)&sqi_q[r >> 2])[r & 3];
    const float d2 = fmaxf(si + sj - 2.0f * acc[r], 0.0f);
    const float gg = __expf(-0.5f * d2);
    gsum += ((i0 + wm + mloc) != gj) ? gg : 0.0f;
  }
#pragma unroll
  for (int off = 32; off; off >>= 1) gsum += __shfl_xor(gsum, off);
  if (lane == 0) wsum[wid] = gsum;
  __syncthreads();
  if (tid == 0) {
    const float w = (rt == ct) ? 1.0f : 2.0f;  // mirrored off-diagonal tiles
    pairP[bid] = w * (wsum[0] + wsum[1] + wsum[2] + wsum[3]);
  }
}

// ---------------------------------------------------------------------------
// Kernel 3: stage-1 reduce. Blocks 0..63 each sum 256 floats of pairP;
// blocks 64..95 each sum 256 floats of spos. Fixed-order tree -> deterministic.
// ---------------------------------------------------------------------------
__global__ void fmicl_reduceA(const float* __restrict__ pairP,
                              const float* __restrict__ spos,
                              double* __restrict__ blockSum) {
  const int b = blockIdx.x;
  const float* src = (b < 64) ? (pairP + b * 256) : (spos + (b - 64) * 256);
  double v = (double)src[threadIdx.x];
#pragma unroll
  for (int off = 32; off; off >>= 1) v += __shfl_xor(v, off);
  __shared__ double ls[4];
  const int lane = threadIdx.x & 63;
  const int wid = threadIdx.x >> 6;
  if (lane == 0) ls[wid] = v;
  __syncthreads();
  if (threadIdx.x == 0) blockSum[b] = ls[0] + ls[1] + ls[2] + ls[3];
}

// ---------------------------------------------------------------------------
// Kernel 4: final reduce + assemble scalar. star_neg = g + EPS exactly, so
// star_mean = negSum/(N(N-1)) + EPS.
// ---------------------------------------------------------------------------
__global__ void fmicl_final(const double* __restrict__ blockSum,
                            float* __restrict__ out) {
  const int l = threadIdx.x;  // 64 threads
  double n = blockSum[l];
#pragma unroll
  for (int off = 32; off; off >>= 1) n += __shfl_xor(n, off);
  double p = (l < 32) ? blockSum[64 + l] : 0.0;
#pragma unroll
  for (int off = 32; off; off >>= 1) p += __shfl_xor(p, off);
  if (l == 0) {
    const double pos_mean = p / (double)NROWS;
    const double star_mean =
        n / ((double)NROWS * (double)(NROWS - 1)) + 1e-8;
    out[0] = (float)(-pos_mean + 1.5 * star_mean);
  }
}

extern "C" void kernel_launch(void* const* d_in, const int* in_sizes, int n_in,
                              void* d_out, int out_size, void* d_ws,
                              size_t ws_size, hipStream_t stream) {
  const float* z1 = (const float*)d_in[0];
  const float* z2 = (const float*)d_in[1];
  float* out = (float*)d_out;
  char* ws = (char*)d_ws;

  // ws layout (every slot rewritten every call; no memset needed):
  //   [0)        pairP    float[16384]        (64 KiB)
  //   [65536)    spos     float[8192]         (32 KiB)
  //   [98304)    blockSum double[96]          (768 B)
  //   [99328)    sq       float[8192]         (32 KiB)
  //   [132096)   zh       f16[8192*128]       (2 MiB), 16B-aligned
  float* pairP = (float*)(ws + 0);
  float* spos = (float*)(ws + 65536);
  double* blockSum = (double*)(ws + 98304);
  float* sq = (float*)(ws + 99328);
  _Float16* zh = (_Float16*)(ws + 132096);

  fmicl_normalize<<<NNORMBLK, 256, 0, stream>>>(z1, z2, sq, zh, spos);
  dim3 grid(NT, NT);
  fmicl_pairwise<<<grid, 256, 0, stream>>>(zh, sq, pairP);
  fmicl_reduceA<<<NREDA, 256, 0, stream>>>(pairP, spos, blockSum);
  fmicl_final<<<1, 64, 0, stream>>>(blockSum, out);
}

// Round 3
// 33.725 us; speedup vs baseline: 6.4554x; 1.2354x over previous
//
#include <hip/hip_runtime.h>

#define NROWS 8192
#define DIM 128
#define NT 64                 // 8192 / 128 tiles per side
#define NPAIRBLK (NT * (NT + 1) / 2)  // 2080 upper-triangular tiles
#define NNORMBLK 2048         // normalize blocks (4 rows each)

typedef _Float16 f16x8 __attribute__((ext_vector_type(8)));
typedef float f32x16 __attribute__((ext_vector_type(16)));

// ---------------------------------------------------------------------------
// Kernel 1: per-row L2 normalize (fp32, as reference). 256 threads = 4 waves,
// one wave per row. Emits zh (f16 normalized z1), sq (fp32 row norms of n1),
// spos[row] (positive-term per-row scalar). No atomics.
// ---------------------------------------------------------------------------
__global__ void fmicl_normalize(const float* __restrict__ z1,
                                const float* __restrict__ z2,
                                float* __restrict__ sq,
                                _Float16* __restrict__ zh,
                                float* __restrict__ spos) {
  const int row = blockIdx.x * 4 + (threadIdx.x >> 6);
  const int lane = threadIdx.x & 63;
  const float* r1 = z1 + (size_t)row * DIM;
  const float* r2 = z2 + (size_t)row * DIM;
  float a0 = r1[lane], a1 = r1[lane + 64];
  float b0 = r2[lane], b1 = r2[lane + 64];
  float s1 = a0 * a0 + a1 * a1;
  float s2 = b0 * b0 + b1 * b1;
#pragma unroll
  for (int off = 32; off; off >>= 1) {
    s1 += __shfl_xor(s1, off);
    s2 += __shfl_xor(s2, off);
  }
  const float inv1 = 1.0f / fmaxf(sqrtf(s1), 1e-12f);
  const float inv2 = 1.0f / fmaxf(sqrtf(s2), 1e-12f);
  const float n1a = a0 * inv1, n1b = a1 * inv1;
  const float n2a = b0 * inv2, n2b = b1 * inv2;
  float sqp = n1a * n1a + n1b * n1b;
  const float da = n1a - n2a, db = n1b - n2b;
  float dp = da * da + db * db;
#pragma unroll
  for (int off = 32; off; off >>= 1) {
    sqp += __shfl_xor(sqp, off);
    dp += __shfl_xor(dp, off);
  }
  zh[(size_t)row * DIM + lane] = (_Float16)n1a;
  zh[(size_t)row * DIM + lane + 64] = (_Float16)n1b;
  if (lane == 0) {
    sq[row] = sqp;
    spos[row] = logf(expf(-0.5f * dp) + 1e-8f) + 1.0f;  // f'(g_pos)
  }
}

// ---------------------------------------------------------------------------
// Kernel 2: fused Gram 128x128 tile + exp epilogue. 512 threads = 8 waves
// (2 rows x 4 cols of 64x32 wave-tiles); each wave runs TWO independent
// 32x32 MFMA chains (8 x v_mfma_f32_32x32x16_f16 over K=128) for MFMA ILP.
// LDS 64 KiB (two 128x128 f16 panels) -> 2 blocks/CU = 16 waves/CU.
// 1D triangular grid (2080 blocks, ct>=rt), integer-exact decode; off-diag
// tiles weighted x2. Bytes staged per pair: 4 B (halved vs 64x64 tiles).
// Swizzle ^(r&15) on 16B granules: 2-way read aliasing (free per m136).
// ---------------------------------------------------------------------------
__global__ __launch_bounds__(512, 4) void fmicl_pairwise(
    const _Float16* __restrict__ zh,
    const float* __restrict__ sq,
    float* __restrict__ pairP) {
  __shared__ _Float16 As[128 * DIM];
  __shared__ _Float16 Bs[128 * DIM];
  __shared__ float wsum[8];

  const int tid = threadIdx.x;
  const int bid = blockIdx.x;

  // ---- triangular decode: row rt has (NT-rt) tiles; C(r) = r*NT - r(r-1)/2
  int rt = (int)(64.5f - sqrtf(64.5f * 64.5f - 2.0f * (float)bid));
  if (rt < 0) rt = 0;
  while (rt > 0 && (rt * NT - (rt * (rt - 1)) / 2) > bid) --rt;
  while (((rt + 1) * NT - ((rt + 1) * rt) / 2) <= bid) ++rt;
  const int ct = rt + (bid - (rt * NT - (rt * (rt - 1)) / 2));

  const int lane = tid & 63;
  const int wid = tid >> 6;
  const int i0 = rt << 7;
  const int j0 = ct << 7;

  // ---- stage both panels (coalesced; reg-staged so LDS addr is swizzled) ----
  const uint4* __restrict__ gA = (const uint4*)(zh + (size_t)i0 * DIM);
  const uint4* __restrict__ gB = (const uint4*)(zh + (size_t)j0 * DIM);
  uint4* sA = (uint4*)As;
  uint4* sB = (uint4*)Bs;
#pragma unroll
  for (int it = 0; it < 4; ++it) {
    const int g = tid + it * 512;   // 128 rows x 16 granules (16B)
    const int r = g >> 4;
    const int c = g & 15;
    const uint4 va = gA[g];
    const uint4 vb = gB[g];
    const int cs = c ^ (r & 15);
    sA[r * 16 + cs] = va;
    sB[r * 16 + cs] = vb;
  }
  __syncthreads();

  const int l31 = lane & 31;
  const int lhi = lane >> 5;
  const int wm = (wid >> 2) * 64;   // wave sub-tile origin inside 128x128
  const int wn = (wid & 3) * 32;

  const int ra0 = wm + l31;
  const int ra1 = wm + 32 + l31;
  const int rb = wn + l31;
  f32x16 acc0 = {}, acc1 = {};
#pragma unroll
  for (int ks = 0; ks < 8; ++ks) {
    const int kg = ks * 2 + lhi;
    const uint4 va0 = sA[ra0 * 16 + (kg ^ (ra0 & 15))];
    const uint4 va1 = sA[ra1 * 16 + (kg ^ (ra1 & 15))];
    const uint4 vb = sB[rb * 16 + (kg ^ (rb & 15))];
    const f16x8 bfr = __builtin_bit_cast(f16x8, vb);
    acc0 = __builtin_amdgcn_mfma_f32_32x32x16_f16(
        __builtin_bit_cast(f16x8, va0), bfr, acc0, 0, 0, 0);
    acc1 = __builtin_amdgcn_mfma_f32_32x32x16_f16(
        __builtin_bit_cast(f16x8, va1), bfr, acc1, 0, 0, 0);
  }

  // ---- epilogue: d2 = sq_i + sq_j - 2*dot; g = exp(-d2/2); mask diagonal ----
  // C/D layout (32x32): col = lane&31, row = (reg&3)+8*(reg>>2)+4*(lane>>5)
  const int gj = j0 + wn + l31;
  const float sj = sq[gj];
  float gsum = 0.0f;
#pragma unroll
  for (int mi = 0; mi < 2; ++mi) {
    const f32x16& acc = mi ? acc1 : acc0;
    const int mbase = wm + mi * 32;
    float4 sqi_q[4];
#pragma unroll
    for (int q = 0; q < 4; ++q)
      sqi_q[q] = *(const float4*)&sq[i0 + mbase + 4 * lhi + 8 * q];
#pragma unroll
    for (int r = 0; r < 16; ++r) {
      const int mloc = (r & 3) + 4 * lhi + 8 * (r >> 2);
      const float si = ((const float*)&sqi_q[r >> 2])[r & 3];
      const float d2 = fmaxf(si + sj - 2.0f * acc[r], 0.0f);
      const float gg = __expf(-0.5f * d2);
      gsum += ((i0 + mbase + mloc) != gj) ? gg : 0.0f;
    }
  }
#pragma unroll
  for (int off = 32; off; off >>= 1) gsum += __shfl_xor(gsum, off);
  if (lane == 0) wsum[wid] = gsum;
  __syncthreads();
  if (tid == 0) {
    const float w = (rt == ct) ? 1.0f : 2.0f;  // mirrored off-diagonal tiles
    float s = 0.0f;
#pragma unroll
    for (int k = 0; k < 8; ++k) s += wsum[k];
    pairP[bid] = w * s;
  }
}

// ---------------------------------------------------------------------------
// Kernel 3: single-block fused reduce + assemble scalar.
// star_neg = g + EPS exactly, so star_mean = negSum/(N(N-1)) + EPS.
// Fixed-order tree -> deterministic.
// ---------------------------------------------------------------------------
__global__ void fmicl_reduce(const float* __restrict__ pairP,
                             const float* __restrict__ spos,
                             float* __restrict__ out) {
  const int t = threadIdx.x;  // 1024 threads = 16 waves
  double nsum = (double)pairP[t] + (double)pairP[t + 1024];
  if (t < NPAIRBLK - 2048) nsum += (double)pairP[t + 2048];
  double psum = 0.0;
#pragma unroll
  for (int k = 0; k < 8; ++k) psum += (double)spos[t + 1024 * k];
#pragma unroll
  for (int off = 32; off; off >>= 1) {
    nsum += __shfl_xor(nsum, off);
    psum += __shfl_xor(psum, off);
  }
  __shared__ double ls[2][16];
  const int lane = t & 63;
  const int wid = t >> 6;
  if (lane == 0) {
    ls[0][wid] = nsum;
    ls[1][wid] = psum;
  }
  __syncthreads();
  if (t == 0) {
    double n = 0.0, p = 0.0;
#pragma unroll
    for (int k = 0; k < 16; ++k) {
      n += ls[0][k];
      p += ls[1][k];
    }
    const double pos_mean = p / (double)NROWS;
    const double star_mean = n / ((double)NROWS * (double)(NROWS - 1)) + 1e-8;
    out[0] = (float)(-pos_mean + 1.5 * star_mean);
  }
}

extern "C" void kernel_launch(void* const* d_in, const int* in_sizes, int n_in,
                              void* d_out, int out_size, void* d_ws,
                              size_t ws_size, hipStream_t stream) {
  const float* z1 = (const float*)d_in[0];
  const float* z2 = (const float*)d_in[1];
  float* out = (float*)d_out;
  char* ws = (char*)d_ws;

  // ws layout (every slot rewritten every call; no memset needed):
  //   [0)      pairP float[2080]   (pad to 16 KiB)
  //   [16384)  spos  float[8192]   (32 KiB)
  //   [49152)  sq    float[8192]   (32 KiB)
  //   [81920)  zh    f16[8192*128] (2 MiB), 16B-aligned
  float* pairP = (float*)(ws + 0);
  float* spos = (float*)(ws + 16384);
  float* sq = (float*)(ws + 49152);
  _Float16* zh = (_Float16*)(ws + 81920);

  fmicl_normalize<<<NNORMBLK, 256, 0, stream>>>(z1, z2, sq, zh, spos);
  fmicl_pairwise<<<NPAIRBLK, 512, 0, stream>>>(zh, sq, pairP);
  fmicl_reduce<<<1, 1024, 0, stream>>>(pairP, spos, out);
}